// Round 3
// baseline (245.348 us; speedup 1.0000x reference)
//
#include <hip/hip_runtime.h>
#include <math.h>

#define S_LEN 2048
#define D_DIM 128
#define BHN   32
#define NKT   32   // KV tiles of 64
#define NQT   32   // Q tiles of 64
#define NITEMS (BHN * NQT)   // 1024 (bh, qi) work items
#define LOG2E 1.44269504088896340736f

typedef _Float16 f16;
typedef __attribute__((ext_vector_type(4))) _Float16 f16x4;
typedef __attribute__((ext_vector_type(8))) _Float16 f16x8;
typedef __attribute__((ext_vector_type(4))) float    f32x4;

// dynamic work-item counter (zeroed by prep_kernel, consumed by attn_kernel;
// kernel-boundary ordering on the stream makes the zero visible to atomics)
__device__ int g_counter;

__device__ __forceinline__ void async_cp16(const void* g, void* l) {
  __builtin_amdgcn_global_load_lds(
      (const __attribute__((address_space(1))) unsigned int*)g,
      (__attribute__((address_space(3))) unsigned int*)l,
      16, 0, 0);
}

// ---- fused prepass: one block per (bh, jt) 64-row tile (unchanged; proven).
__global__ __launch_bounds__(256) void prep_kernel(const float* __restrict__ k,
                                                   const float* __restrict__ v,
                                                   f16* __restrict__ kw,
                                                   f16* __restrict__ vtw) {
  __shared__ f16 Vimg[D_DIM * 64];   // 16 KB, final swizzled V^T image

  if (blockIdx.x == 0 && threadIdx.x == 0) g_counter = 0;

  const int bx = blockIdx.x;
  const int bh = bx >> 5;
  const int jt = bx & 31;
  const int t  = threadIdx.x;

  // ---- K: fp32 -> f16 swizzled tile [r(64)][chunk'(16)][8], chunk' = kd^(r&15)
  {
    const float* kbase = k + ((size_t)bh * S_LEN + jt * 64) * D_DIM;
    f16* ktile = kw + (((size_t)bh * NKT + jt) * 64) * (size_t)D_DIM;
#pragma unroll
    for (int i = 0; i < 4; ++i) {
      int unit = i * 256 + t;
      int kd = unit & 15;
      int r  = unit >> 4;
      const float* src = kbase + r * D_DIM + kd * 8;
      float4 a = *(const float4*)src;
      float4 b = *(const float4*)(src + 4);
      f16x8 vv;
      vv[0]=(f16)a.x; vv[1]=(f16)a.y; vv[2]=(f16)a.z; vv[3]=(f16)a.w;
      vv[4]=(f16)b.x; vv[5]=(f16)b.y; vv[6]=(f16)b.z; vv[7]=(f16)b.w;
      *(f16x8*)(ktile + r * D_DIM + ((kd ^ (r & 15)) * 8)) = vv;
    }
  }

  // ---- V: fp32 -> f16 transposed tile [d(128)][chunk'(8)][8], chunk' = kc^(d&7)
  {
    const int rq = t >> 4;
    const int dg = t & 15;
    const float* base = v + (((size_t)bh * S_LEN + jt * 64 + rq * 4) * D_DIM + dg * 8);
    float rows[4][8];
#pragma unroll
    for (int rr = 0; rr < 4; ++rr) {
      float4 aa = *(const float4*)(base + rr * D_DIM);
      float4 bb = *(const float4*)(base + rr * D_DIM + 4);
      rows[rr][0]=aa.x; rows[rr][1]=aa.y; rows[rr][2]=aa.z; rows[rr][3]=aa.w;
      rows[rr][4]=bb.x; rows[rr][5]=bb.y; rows[rr][6]=bb.z; rows[rr][7]=bb.w;
    }
    const int kc = rq >> 1;
    const int kk = (rq & 1) * 4;
#pragma unroll
    for (int dd0 = 0; dd0 < 8; ++dd0) {
      int dd = (dd0 + dg) & 7;
      int d  = dg * 8 + dd;
      f16x4 p;
      p[0]=(f16)rows[0][dd]; p[1]=(f16)rows[1][dd];
      p[2]=(f16)rows[2][dd]; p[3]=(f16)rows[3][dd];
      *(f16x4*)(Vimg + d * 64 + ((kc ^ dd) * 8) + kk) = p;
    }
    __syncthreads();
    f16* vtile = vtw + ((size_t)bh * NKT + jt) * (size_t)(D_DIM * 64);
#pragma unroll
    for (int i = 0; i < 4; ++i) {
      int idx = i * 256 + t;
      *(f16x8*)(vtile + idx * 8) = *(const f16x8*)(Vimg + idx * 8);
    }
  }
}

// ---- main: flash attention with TRANSPOSED scores (S^T = K Q^T).
// R4: revert to the PROVEN R2 datapath (Plds-based PV, always-rescale, no
// launch-bounds min -> 88 VGPR, no spills). Occupancy fix done without
// touching the datapath:
//  (1) item broadcast aliased into Plds[0] (row 0 belongs to wave 0, lockstep
//      with writer t0; read happens before any P write) -> LDS exactly 40960
//      -> 4 blocks/CU. Grid 1024.
//  (2) snake item order: qi(g,k) = 8g + (g odd ? k : 7-k), bh = item&31.
//      Any stride-256 rank sample {r, r+256, r+512, r+768} sums to 66
//      block-iters (= mean) AND shares the same bh -> per-CU balance + L2
//      locality (R2's dynamic scatter pushed FETCH 42->174 MB).
__global__ __launch_bounds__(256) void attn_kernel(const float* __restrict__ q,
                                                   const f16* __restrict__ kw,
                                                   const f16* __restrict__ vtw,
                                                   const float* __restrict__ am,
                                                   const float* __restrict__ hm,
                                                   float* __restrict__ out) {
  __shared__ f16 Klds[64 * 128];   // 16 KB: K tile, swizzled
  __shared__ f16 Vlds[64 * 128];   // 16 KB: V^T tile, swizzled
  __shared__ f16 Plds[64 * 64];    // 8 KB: P; Plds[0..1] doubles as item bcast

  const int t    = threadIdx.x;
  const int w    = t >> 6;
  const int lane = t & 63;
  const int c    = lane & 15;
  const int quad = lane >> 4;
  const int R    = w * 16 + c;     // this lane's Q-row within the 64-row tile

  f32x4 zero4; zero4[0]=0.f; zero4[1]=0.f; zero4[2]=0.f; zero4[3]=0.f;

  for (;;) {
    if (t == 0) ((volatile int*)Plds)[0] = atomicAdd(&g_counter, 1);
    __syncthreads();                 // item visible; also fences prior P reads
    const int item = ((volatile int*)Plds)[0];
    if (item >= NITEMS) break;

    // snake order: per-CU stride-256 pickup sums qi to 62 and shares bh
    const int g  = item >> 8;
    const int k8 = (item >> 5) & 7;
    const int bh = item & 31;
    const int qi = (g << 3) + ((g & 1) ? k8 : 7 - k8);
    const int b  = bh >> 4;
    const int h  = bh & 15;
    const int qb = qi * 64;

    // Q fragments (pre-scaled by log2e). Used as the B operand of S^T = K Q^T:
    // B[k=quad*8+j][n=lane&15] == Q[row c][k] — identical register content to A-layout.
    f16x8 qf[4];
    {
      const float* qsrc = q + (((size_t)bh * S_LEN + qb + R) * D_DIM + quad * 8);
#pragma unroll
      for (int ks = 0; ks < 4; ++ks) {
        float4 a  = *(const float4*)(qsrc + ks * 32);
        float4 bb = *(const float4*)(qsrc + ks * 32 + 4);
        f16x8 vv;
        vv[0]=(f16)(a.x*LOG2E);  vv[1]=(f16)(a.y*LOG2E);  vv[2]=(f16)(a.z*LOG2E);  vv[3]=(f16)(a.w*LOG2E);
        vv[4]=(f16)(bb.x*LOG2E); vv[5]=(f16)(bb.y*LOG2E); vv[6]=(f16)(bb.z*LOG2E); vv[7]=(f16)(bb.w*LOG2E);
        qf[ks] = vv;
      }
    }

    const float hmv  = hm[h];
    const float* amp = am + (size_t)b * S_LEN;

    f32x4 oacc[8];                       // O rows quad*4+r, cols dt*16+c
#pragma unroll
    for (int dt = 0; dt < 8; ++dt) oacc[dt] = zero4;
    float mrow = -INFINITY;              // running max of Q-row R (uniform across quads)
    float lrow = 0.f;                    // per-quad PARTIAL sum for Q-row R

    const f16* ktiles = kw  + (size_t)bh * NKT * (64 * 128);
    const f16* vtiles = vtw + (size_t)bh * NKT * (64 * 128);

    for (int j = 0; j <= qi; ++j) {
      __syncthreads();   // (A) all waves done reading previous K/V tiles
      {
        const f16* kg = ktiles + (size_t)j * (64 * 128) + (w * 4) * 512 + lane * 8;
        const f16* vg = vtiles + (size_t)j * (64 * 128) + (w * 4) * 512 + lane * 8;
        f16* kl = Klds + (w * 4) * 512;
        f16* vl = Vlds + (w * 4) * 512;
#pragma unroll
        for (int i = 0; i < 4; ++i) async_cp16(kg + i * 512, kl + i * 512);
#pragma unroll
        for (int i = 0; i < 4; ++i) async_cp16(vg + i * 512, vl + i * 512);
      }
      // attn_mask for this lane's 16 KV cols: quad-broadcast float4 loads (L1-served)
      float amv[4][4];
#pragma unroll
      for (int nt = 0; nt < 4; ++nt) {
        float4 a4 = *(const float4*)(amp + j * 64 + nt * 16 + quad * 4);
        amv[nt][0]=a4.x; amv[nt][1]=a4.y; amv[nt][2]=a4.z; amv[nt][3]=a4.w;
      }
      __syncthreads();   // (B) tiles resident

      // S^T = K (Q*log2e)^T : sacc[nt][r] = S'[kv = j*64+nt*16+quad*4+r][qrow = R]
      f32x4 sacc[4];
#pragma unroll
      for (int nt = 0; nt < 4; ++nt) sacc[nt] = zero4;
      __builtin_amdgcn_s_setprio(1);
#pragma unroll
      for (int ks = 0; ks < 4; ++ks) {
#pragma unroll
        for (int nt = 0; nt < 4; ++nt) {
          const f16x8 kf = *(const f16x8*)(Klds + (nt * 16 + c) * 128 + (((ks * 4 + quad) ^ c) * 8));
          sacc[nt] = __builtin_amdgcn_mfma_f32_16x16x32_f16(kf, qf[ks], sacc[nt], 0, 0, 0);
        }
      }
      __builtin_amdgcn_s_setprio(0);

      if (j == qi) {   // causal mask, diagonal tile only
#pragma unroll
        for (int nt = 0; nt < 4; ++nt)
#pragma unroll
          for (int r = 0; r < 4; ++r) {
            int col = nt * 16 + quad * 4 + r;     // within-tile KV col
            if (col > R) sacc[nt][r] = -INFINITY; // row within tile = R (qb cancels)
          }
      }
#pragma unroll
      for (int nt = 0; nt < 4; ++nt)
#pragma unroll
        for (int r = 0; r < 4; ++r) sacc[nt][r] = fmaf(amv[nt][r], LOG2E, sacc[nt][r]);

      // online softmax: in-lane max over this lane's 16 cols, then 2 shuffles
      float m16 = sacc[0][0];
#pragma unroll
      for (int nt = 0; nt < 4; ++nt)
#pragma unroll
        for (int r = 0; r < 4; ++r) m16 = fmaxf(m16, sacc[nt][r]);
      m16 = fmaxf(m16, __shfl_xor(m16, 16));
      m16 = fmaxf(m16, __shfl_xor(m16, 32));
      float mnew  = fmaxf(mrow, m16);
      float alpha = exp2f(mrow - mnew);
      mrow = mnew;

      float psum = 0.f;
#pragma unroll
      for (int nt = 0; nt < 4; ++nt)
#pragma unroll
        for (int r = 0; r < 4; ++r) {
          sacc[nt][r] = exp2f(sacc[nt][r] - mnew);
          psum += sacc[nt][r];
        }
      lrow = lrow * alpha + psum;   // per-quad partial; reduced at epilogue

      // P write: 4 consecutive k per (nt) -> one b64, even-XOR swizzle keeps pairs
#pragma unroll
      for (int nt = 0; nt < 4; ++nt) {
        f16x4 p;
        p[0]=(f16)sacc[nt][0]; p[1]=(f16)sacc[nt][1];
        p[2]=(f16)sacc[nt][2]; p[3]=(f16)sacc[nt][3];
        int ch = (nt * 4 + quad) ^ ((c & 7) << 1);
        *(f16x4*)(Plds + R * 64 + ch * 4) = p;
      }

      // alpha for O rows quad*4+r lives at lane with (lane&15)==quad*4+r
      float al[4];
#pragma unroll
      for (int r = 0; r < 4; ++r) al[r] = __shfl(alpha, (lane & 48) | (quad * 4 + r));
#pragma unroll
      for (int dt = 0; dt < 8; ++dt)
#pragma unroll
        for (int r = 0; r < 4; ++r) oacc[dt][r] *= al[r];

      // O += P V : A-frag = single b128 from swizzled Plds (pair-preserving XOR)
      __builtin_amdgcn_s_setprio(1);
#pragma unroll
      for (int ks2 = 0; ks2 < 2; ++ks2) {
        int ch = (ks2 * 8 + quad * 2) ^ ((c & 7) << 1);
        const f16x8 af = *(const f16x8*)(Plds + R * 64 + ch * 4);
#pragma unroll
        for (int dt = 0; dt < 8; ++dt) {
          const f16x8 bf = *(const f16x8*)(Vlds + (dt * 16 + c) * 64 + (((ks2 * 4 + quad) ^ (c & 7)) * 8));
          oacc[dt] = __builtin_amdgcn_mfma_f32_16x16x32_f16(af, bf, oacc[dt], 0, 0, 0);
        }
      }
      __builtin_amdgcn_s_setprio(0);
    }

    // epilogue: reduce l across quads, broadcast to O rows, out = hm * O / l
    float lr = lrow;
    lr += __shfl_xor(lr, 16);
    lr += __shfl_xor(lr, 32);
    float linv = hmv / lr;
    float rinv[4];
#pragma unroll
    for (int r = 0; r < 4; ++r) rinv[r] = __shfl(linv, (lane & 48) | (quad * 4 + r));

    float* obase = out + (((size_t)bh * S_LEN + qb + w * 16) * D_DIM);
#pragma unroll
    for (int dt = 0; dt < 8; ++dt)
#pragma unroll
      for (int r = 0; r < 4; ++r)
        obase[(quad * 4 + r) * D_DIM + dt * 16 + c] = oacc[dt][r] * rinv[r];
  }
}

extern "C" void kernel_launch(void* const* d_in, const int* in_sizes, int n_in,
                              void* d_out, int out_size, void* d_ws, size_t ws_size,
                              hipStream_t stream) {
  const float* q  = (const float*)d_in[0];
  const float* k  = (const float*)d_in[1];
  const float* v  = (const float*)d_in[2];
  const float* am = (const float*)d_in[3];
  const float* hm = (const float*)d_in[4];
  float* out = (float*)d_out;

  f16* kw  = (f16*)d_ws;                              // 16.78 MB
  f16* vtw = kw + (size_t)BHN * S_LEN * D_DIM;        // 16.78 MB

  prep_kernel<<<1024, 256, 0, stream>>>(k, v, kw, vtw);
  attn_kernel<<<1024, 256, 0, stream>>>(q, kw, vtw, am, hm, out);
}

// Round 4
// 210.301 us; speedup vs baseline: 1.1666x; 1.1666x over previous
//
#include <hip/hip_runtime.h>
#include <math.h>

#define S_LEN 2048
#define D_DIM 128
#define BHN   32
#define NKT   32   // KV tiles of 64
#define NQT   32   // Q tiles of 64
#define NGRP  8    // per-XCD work groups
#define ITEMS_PER_GRP 128   // 4 bh x 32 qi
#define LOG2E 1.44269504088896340736f

typedef _Float16 f16;
typedef __attribute__((ext_vector_type(4))) _Float16 f16x4;
typedef __attribute__((ext_vector_type(8))) _Float16 f16x8;
typedef __attribute__((ext_vector_type(4))) float    f32x4;

// per-XCD-group work counters (zeroed by prep_kernel, consumed by attn_kernel;
// kernel-boundary ordering on the stream makes the zeroes visible to atomics)
__device__ int g_counters[NGRP];

__device__ __forceinline__ void async_cp16(const void* g, void* l) {
  __builtin_amdgcn_global_load_lds(
      (const __attribute__((address_space(1))) unsigned int*)g,
      (__attribute__((address_space(3))) unsigned int*)l,
      16, 0, 0);
}

// ---- fused prepass: one block per (bh, jt) 64-row tile (unchanged; proven).
__global__ __launch_bounds__(256) void prep_kernel(const float* __restrict__ k,
                                                   const float* __restrict__ v,
                                                   f16* __restrict__ kw,
                                                   f16* __restrict__ vtw) {
  __shared__ f16 Vimg[D_DIM * 64];   // 16 KB, final swizzled V^T image

  if (blockIdx.x == 0 && threadIdx.x < NGRP) g_counters[threadIdx.x] = 0;

  const int bx = blockIdx.x;
  const int bh = bx >> 5;
  const int jt = bx & 31;
  const int t  = threadIdx.x;

  // ---- K: fp32 -> f16 swizzled tile [r(64)][chunk'(16)][8], chunk' = kd^(r&15)
  {
    const float* kbase = k + ((size_t)bh * S_LEN + jt * 64) * D_DIM;
    f16* ktile = kw + (((size_t)bh * NKT + jt) * 64) * (size_t)D_DIM;
#pragma unroll
    for (int i = 0; i < 4; ++i) {
      int unit = i * 256 + t;
      int kd = unit & 15;
      int r  = unit >> 4;
      const float* src = kbase + r * D_DIM + kd * 8;
      float4 a = *(const float4*)src;
      float4 b = *(const float4*)(src + 4);
      f16x8 vv;
      vv[0]=(f16)a.x; vv[1]=(f16)a.y; vv[2]=(f16)a.z; vv[3]=(f16)a.w;
      vv[4]=(f16)b.x; vv[5]=(f16)b.y; vv[6]=(f16)b.z; vv[7]=(f16)b.w;
      *(f16x8*)(ktile + r * D_DIM + ((kd ^ (r & 15)) * 8)) = vv;
    }
  }

  // ---- V: fp32 -> f16 transposed tile [d(128)][chunk'(8)][8], chunk' = kc^(d&7)
  {
    const int rq = t >> 4;
    const int dg = t & 15;
    const float* base = v + (((size_t)bh * S_LEN + jt * 64 + rq * 4) * D_DIM + dg * 8);
    float rows[4][8];
#pragma unroll
    for (int rr = 0; rr < 4; ++rr) {
      float4 aa = *(const float4*)(base + rr * D_DIM);
      float4 bb = *(const float4*)(base + rr * D_DIM + 4);
      rows[rr][0]=aa.x; rows[rr][1]=aa.y; rows[rr][2]=aa.z; rows[rr][3]=aa.w;
      rows[rr][4]=bb.x; rows[rr][5]=bb.y; rows[rr][6]=bb.z; rows[rr][7]=bb.w;
    }
    const int kc = rq >> 1;
    const int kk = (rq & 1) * 4;
#pragma unroll
    for (int dd0 = 0; dd0 < 8; ++dd0) {
      int dd = (dd0 + dg) & 7;
      int d  = dg * 8 + dd;
      f16x4 p;
      p[0]=(f16)rows[0][dd]; p[1]=(f16)rows[1][dd];
      p[2]=(f16)rows[2][dd]; p[3]=(f16)rows[3][dd];
      *(f16x4*)(Vimg + d * 64 + ((kc ^ dd) * 8) + kk) = p;
    }
    __syncthreads();
    f16* vtile = vtw + ((size_t)bh * NKT + jt) * (size_t)(D_DIM * 64);
#pragma unroll
    for (int i = 0; i < 4; ++i) {
      int idx = i * 256 + t;
      *(f16x8*)(vtile + idx * 8) = *(const f16x8*)(Vimg + idx * 8);
    }
  }
}

// ---- main: flash attention with TRANSPOSED scores (S^T = K Q^T).
// R5: R2's proven datapath + per-XCD work queues.
//  - 8 counters; block group = blockIdx.x & 7 (empirical round-robin block->XCD;
//    correctness independent of mapping). Group x owns bh in {4x..4x+3} x 32 qi
//    = 128 items -> per-XCD K/V working set 4 MB = one XCD L2 (R4 scattered all
//    32 bh -> 32 MB on 4 MB L2 -> FETCH 220 MB, L3-latency loads).
//  - LPT in-group: rank r -> qi = 31-(r>>2), bh = 4x+(r&3). Heavy first,
//    light items backfill (real stealing: 96 blocks per group, 128 items).
//  - Grid 768 = 3 blocks/CU (LDS 41472*3 = 124 KB fits; 12 waves/CU vs R2's 8).
__global__ __launch_bounds__(256) void attn_kernel(const float* __restrict__ q,
                                                   const f16* __restrict__ kw,
                                                   const f16* __restrict__ vtw,
                                                   const float* __restrict__ am,
                                                   const float* __restrict__ hm,
                                                   float* __restrict__ out) {
  __shared__ f16 Klds[64 * 128];   // 16 KB: K tile, swizzled
  __shared__ f16 Vlds[64 * 128];   // 16 KB: V^T tile, swizzled
  __shared__ f16 Plds[64 * 64];    // 8 KB: P, 4-elem chunks, chunk' = ch ^ ((row&7)<<1)
  __shared__ int sh_item;

  const int grp  = blockIdx.x & (NGRP - 1);
  const int t    = threadIdx.x;
  const int w    = t >> 6;
  const int lane = t & 63;
  const int c    = lane & 15;
  const int quad = lane >> 4;
  const int R    = w * 16 + c;     // this lane's Q-row within the 64-row tile

  f32x4 zero4; zero4[0]=0.f; zero4[1]=0.f; zero4[2]=0.f; zero4[3]=0.f;

  for (;;) {
    if (t == 0) sh_item = atomicAdd(&g_counters[grp], 1);
    __syncthreads();                 // item visible; also fences prior P reads
    const int item = sh_item;
    if (item >= ITEMS_PER_GRP) break;

    const int qi = 31 - (item >> 2);      // LPT: heaviest first
    const int bh = grp * 4 + (item & 3);  // group-local bh -> L2 locality
    const int b  = bh >> 4;
    const int h  = bh & 15;
    const int qb = qi * 64;

    // Q fragments (pre-scaled by log2e). Used as the B operand of S^T = K Q^T:
    // B[k=quad*8+j][n=lane&15] == Q[row c][k] — identical register content to A-layout.
    f16x8 qf[4];
    {
      const float* qsrc = q + (((size_t)bh * S_LEN + qb + R) * D_DIM + quad * 8);
#pragma unroll
      for (int ks = 0; ks < 4; ++ks) {
        float4 a  = *(const float4*)(qsrc + ks * 32);
        float4 bb = *(const float4*)(qsrc + ks * 32 + 4);
        f16x8 vv;
        vv[0]=(f16)(a.x*LOG2E);  vv[1]=(f16)(a.y*LOG2E);  vv[2]=(f16)(a.z*LOG2E);  vv[3]=(f16)(a.w*LOG2E);
        vv[4]=(f16)(bb.x*LOG2E); vv[5]=(f16)(bb.y*LOG2E); vv[6]=(f16)(bb.z*LOG2E); vv[7]=(f16)(bb.w*LOG2E);
        qf[ks] = vv;
      }
    }

    const float hmv  = hm[h];
    const float* amp = am + (size_t)b * S_LEN;

    f32x4 oacc[8];                       // O rows quad*4+r, cols dt*16+c
#pragma unroll
    for (int dt = 0; dt < 8; ++dt) oacc[dt] = zero4;
    float mrow = -INFINITY;              // running max of Q-row R (uniform across quads)
    float lrow = 0.f;                    // per-quad PARTIAL sum for Q-row R

    const f16* ktiles = kw  + (size_t)bh * NKT * (64 * 128);
    const f16* vtiles = vtw + (size_t)bh * NKT * (64 * 128);

    for (int j = 0; j <= qi; ++j) {
      __syncthreads();   // (A) all waves done reading previous K/V tiles
      {
        const f16* kg = ktiles + (size_t)j * (64 * 128) + (w * 4) * 512 + lane * 8;
        const f16* vg = vtiles + (size_t)j * (64 * 128) + (w * 4) * 512 + lane * 8;
        f16* kl = Klds + (w * 4) * 512;
        f16* vl = Vlds + (w * 4) * 512;
#pragma unroll
        for (int i = 0; i < 4; ++i) async_cp16(kg + i * 512, kl + i * 512);
#pragma unroll
        for (int i = 0; i < 4; ++i) async_cp16(vg + i * 512, vl + i * 512);
      }
      // attn_mask for this lane's 16 KV cols: quad-broadcast float4 loads (L1-served)
      float amv[4][4];
#pragma unroll
      for (int nt = 0; nt < 4; ++nt) {
        float4 a4 = *(const float4*)(amp + j * 64 + nt * 16 + quad * 4);
        amv[nt][0]=a4.x; amv[nt][1]=a4.y; amv[nt][2]=a4.z; amv[nt][3]=a4.w;
      }
      __syncthreads();   // (B) tiles resident

      // S^T = K (Q*log2e)^T : sacc[nt][r] = S'[kv = j*64+nt*16+quad*4+r][qrow = R]
      f32x4 sacc[4];
#pragma unroll
      for (int nt = 0; nt < 4; ++nt) sacc[nt] = zero4;
      __builtin_amdgcn_s_setprio(1);
#pragma unroll
      for (int ks = 0; ks < 4; ++ks) {
#pragma unroll
        for (int nt = 0; nt < 4; ++nt) {
          const f16x8 kf = *(const f16x8*)(Klds + (nt * 16 + c) * 128 + (((ks * 4 + quad) ^ c) * 8));
          sacc[nt] = __builtin_amdgcn_mfma_f32_16x16x32_f16(kf, qf[ks], sacc[nt], 0, 0, 0);
        }
      }
      __builtin_amdgcn_s_setprio(0);

      if (j == qi) {   // causal mask, diagonal tile only
#pragma unroll
        for (int nt = 0; nt < 4; ++nt)
#pragma unroll
          for (int r = 0; r < 4; ++r) {
            int col = nt * 16 + quad * 4 + r;     // within-tile KV col
            if (col > R) sacc[nt][r] = -INFINITY; // row within tile = R (qb cancels)
          }
      }
#pragma unroll
      for (int nt = 0; nt < 4; ++nt)
#pragma unroll
        for (int r = 0; r < 4; ++r) sacc[nt][r] = fmaf(amv[nt][r], LOG2E, sacc[nt][r]);

      // online softmax: in-lane max over this lane's 16 cols, then 2 shuffles
      float m16 = sacc[0][0];
#pragma unroll
      for (int nt = 0; nt < 4; ++nt)
#pragma unroll
        for (int r = 0; r < 4; ++r) m16 = fmaxf(m16, sacc[nt][r]);
      m16 = fmaxf(m16, __shfl_xor(m16, 16));
      m16 = fmaxf(m16, __shfl_xor(m16, 32));
      float mnew  = fmaxf(mrow, m16);
      float alpha = exp2f(mrow - mnew);
      mrow = mnew;

      float psum = 0.f;
#pragma unroll
      for (int nt = 0; nt < 4; ++nt)
#pragma unroll
        for (int r = 0; r < 4; ++r) {
          sacc[nt][r] = exp2f(sacc[nt][r] - mnew);
          psum += sacc[nt][r];
        }
      lrow = lrow * alpha + psum;   // per-quad partial; reduced at epilogue

      // P write: 4 consecutive k per (nt) -> one b64, even-XOR swizzle keeps pairs
#pragma unroll
      for (int nt = 0; nt < 4; ++nt) {
        f16x4 p;
        p[0]=(f16)sacc[nt][0]; p[1]=(f16)sacc[nt][1];
        p[2]=(f16)sacc[nt][2]; p[3]=(f16)sacc[nt][3];
        int ch = (nt * 4 + quad) ^ ((c & 7) << 1);
        *(f16x4*)(Plds + R * 64 + ch * 4) = p;
      }

      // alpha for O rows quad*4+r lives at lane with (lane&15)==quad*4+r
      float al[4];
#pragma unroll
      for (int r = 0; r < 4; ++r) al[r] = __shfl(alpha, (lane & 48) | (quad * 4 + r));
#pragma unroll
      for (int dt = 0; dt < 8; ++dt)
#pragma unroll
        for (int r = 0; r < 4; ++r) oacc[dt][r] *= al[r];

      // O += P V : A-frag = single b128 from swizzled Plds (pair-preserving XOR)
      __builtin_amdgcn_s_setprio(1);
#pragma unroll
      for (int ks2 = 0; ks2 < 2; ++ks2) {
        int ch = (ks2 * 8 + quad * 2) ^ ((c & 7) << 1);
        const f16x8 af = *(const f16x8*)(Plds + R * 64 + ch * 4);
#pragma unroll
        for (int dt = 0; dt < 8; ++dt) {
          const f16x8 bf = *(const f16x8*)(Vlds + (dt * 16 + c) * 64 + (((ks2 * 4 + quad) ^ (c & 7)) * 8));
          oacc[dt] = __builtin_amdgcn_mfma_f32_16x16x32_f16(af, bf, oacc[dt], 0, 0, 0);
        }
      }
      __builtin_amdgcn_s_setprio(0);
    }

    // epilogue: reduce l across quads, broadcast to O rows, out = hm * O / l
    float lr = lrow;
    lr += __shfl_xor(lr, 16);
    lr += __shfl_xor(lr, 32);
    float linv = hmv / lr;
    float rinv[4];
#pragma unroll
    for (int r = 0; r < 4; ++r) rinv[r] = __shfl(linv, (lane & 48) | (quad * 4 + r));

    float* obase = out + (((size_t)bh * S_LEN + qb + w * 16) * D_DIM);
#pragma unroll
    for (int dt = 0; dt < 8; ++dt)
#pragma unroll
      for (int r = 0; r < 4; ++r)
        obase[(quad * 4 + r) * D_DIM + dt * 16 + c] = oacc[dt][r] * rinv[r];
  }
}

extern "C" void kernel_launch(void* const* d_in, const int* in_sizes, int n_in,
                              void* d_out, int out_size, void* d_ws, size_t ws_size,
                              hipStream_t stream) {
  const float* q  = (const float*)d_in[0];
  const float* k  = (const float*)d_in[1];
  const float* v  = (const float*)d_in[2];
  const float* am = (const float*)d_in[3];
  const float* hm = (const float*)d_in[4];
  float* out = (float*)d_out;

  f16* kw  = (f16*)d_ws;                              // 16.78 MB
  f16* vtw = kw + (size_t)BHN * S_LEN * D_DIM;        // 16.78 MB

  prep_kernel<<<1024, 256, 0, stream>>>(k, v, kw, vtw);
  attn_kernel<<<768, 256, 0, stream>>>(q, kw, vtw, am, hm, out);
}